// Round 11
// baseline (19.424 us; speedup 1.0000x reference)
//
#include <hip/hip_runtime.h>

// DiscreteLinear: z[b,i] = sum_j weight[a[b],i,j] * x[b,j] + bias[a[b],i]
// B=2048, A=64, D=512.
// R10 = R9 core + (H1) 256B-contiguous DMA segments via BK=64, 2-slot ring
//       + (H2) W DMA for steps 0-1 issued at kernel entry, before the
//         bucket scan (act loads issued first so ballot waits vmcnt(8));
//         raw lgkmcnt0+s_barrier in the bucket so no vmcnt(0) drain.
// R7/R8/R9 all ~19.3us across three different K-loop schedules -> pipeline
// depth/sync is NOT the limiter; remaining suspects are DRAM page locality
// of 128B-strided segments and the serial prologue with HBM idle.

#define NA 64
#define DD 512
#define NB 2048
#define BN 128          // output cols per block
#define NW 8            // waves per block
#define BK 64           // fp32 k per ring step
#define NSTEPS 8        // DD / BK

typedef __bf16  bf16x8  __attribute__((ext_vector_type(8)));
typedef __bf16  bf16x4  __attribute__((ext_vector_type(4)));
typedef float   floatx4 __attribute__((ext_vector_type(4)));

#define GLD16(g, l)                                                         \
  __builtin_amdgcn_global_load_lds(                                         \
      (const __attribute__((address_space(1))) void*)(g),                   \
      (__attribute__((address_space(3))) void*)(l), 16, 0, 0)
#define VMCNT(n) asm volatile("s_waitcnt vmcnt(" #n ")" ::: "memory")
#define LGKMCNT0 asm volatile("s_waitcnt lgkmcnt(0)" ::: "memory")
#define SBAR     __builtin_amdgcn_s_barrier()
#define SCHED0   __builtin_amdgcn_sched_barrier(0)

static __device__ inline bf16x8 cvt8(floatx4 lo, floatx4 hi) {
    bf16x8 r;
    r[0] = (__bf16)lo[0]; r[1] = (__bf16)lo[1];
    r[2] = (__bf16)lo[2]; r[3] = (__bf16)lo[3];
    r[4] = (__bf16)hi[0]; r[5] = (__bf16)hi[1];
    r[6] = (__bf16)hi[2]; r[7] = (__bf16)hi[3];
    return r;
}

__global__ __launch_bounds__(512, 1) void dl_fused(
        const float* __restrict__ x,
        const int*   __restrict__ act,
        const float* __restrict__ weight,
        const float* __restrict__ bias,
        float*       __restrict__ out)
{
    const int a    = blockIdx.x;         // linear id = a + 64*y -> XCD = a%8:
    const int tid  = threadIdx.x;        // the 4 col-tiles of an action share
    const int wave = tid >> 6;           // an XCD -> x/act L2 reuse
    const int lane = tid & 63;
    const int l16  = lane & 15;
    const int kgrp = lane >> 4;
    const int colbase = blockIdx.y * BN;
    const int ncol    = colbase + wave * 16 + l16;

    __shared__ int s_perm[NB];                          // 8 KB
    __shared__ int s_wcnt[NW];
    __shared__ __align__(16) __bf16 Xs[64][DD];         // 64 KB
    __shared__ __align__(16) float  Wl[2][BN][BK];      // 64 KB ring

    const float* wtile = weight + (size_t)a * DD * DD + (size_t)colbase * DD;

    // DMA geometry: wave owns ring rows [wave*16, +16). One call = 4 rows x
    // 256B CONTIGUOUS per row (rr4 = row in quad, u16 = 16B unit in span).
    // Swizzle rule #21: linear LDS dest, source unit pre-XORed by row&15.
    const int rr4 = lane >> 4;            // 0..3
    const int u16 = lane & 15;            // 0..15

    auto issue_step = [&](int slot, int s) {
#pragma unroll
        for (int c = 0; c < 4; ++c) {
            const int riw = c * 4 + rr4;              // row in wave, 0..15
            GLD16(wtile + (size_t)(wave * 16 + riw) * DD + s * BK
                        + ((u16 ^ riw) << 2),
                  (char*)&Wl[slot][wave * 16 + c * 4][0]);
        }
    };

    // ---- (0) act loads first, then early W DMA (ballot waits vmcnt(8)) ----
    const int ibase = wave * (NB / NW);
    int myact[NB / NW / 64];                            // 4, regs
#pragma unroll
    for (int it = 0; it < NB / NW / 64; ++it)
        myact[it] = act[ibase + it * 64 + lane];

    issue_step(0, 0);
    issue_step(1, 1);                                   // 8 DMAs in flight

    // ---- fused bucket (raw barriers: no vmcnt drain) ----
    int wcnt = 0;
#pragma unroll
    for (int it = 0; it < NB / NW / 64; ++it) {
        unsigned long long m = __ballot(myact[it] == a);
        wcnt += (int)__popcll(m);
    }
    if (lane == 0) s_wcnt[wave] = wcnt;
    LGKMCNT0; SBAR;
    int cnt = 0, off = 0;
#pragma unroll
    for (int v = 0; v < NW; ++v) {
        const int c = s_wcnt[v];
        if (v < wave) off += c;
        cnt += c;
    }
    if (cnt == 0) { VMCNT(0); return; }   // drain DMAs before LDS dealloc
#pragma unroll
    for (int it = 0; it < NB / NW / 64; ++it) {
        unsigned long long m = __ballot(myact[it] == a);
        if (myact[it] == a) {
            int pos = off + (int)__popcll(m & ((1ull << lane) - 1ull));
            s_perm[pos] = ibase + it * 64 + lane;
        }
        off += (int)__popcll(m);
    }
    LGKMCNT0; SBAR;                       // publish s_perm

    const float bias_v = bias[(size_t)a * DD + ncol];
    const int   h      = l16 & 7;
    const int   srow   = tid >> 5;        // x staging: 0..15
    const int   skk    = (tid & 31) << 2; // 32 lanes x float4 per row

    for (int m0 = 0; m0 < cnt; m0 += 64) {
        if (m0 > 0) { issue_step(0, 0); issue_step(1, 1); }  // rare 2nd tile
        const int rem    = min(cnt - m0, 64);
        const int nchunk = (rem + 15) >> 4;

        // ---- (1) x loads (clamped, unconditional defs) ----
        floatx4 xv[16];
#pragma unroll
        for (int i = 0; i < 4; ++i) {
            const int r  = srow + 16 * i;
            const int rr = (r < rem) ? r : (rem - 1);
            const float* xr = x + (size_t)s_perm[m0 + rr] * DD;
#pragma unroll
            for (int j = 0; j < 4; ++j)
                xv[i * 4 + j] = *(const floatx4*)(xr + skk + 128 * j);
        }

        // ---- (2) cvt + swizzled Xs write (only live rows) ----
#pragma unroll
        for (int i = 0; i < 4; ++i) {
            const int r = srow + 16 * i;
            if (r < rem) {
                const int rs = (r & 7) << 3;
#pragma unroll
                for (int j = 0; j < 4; ++j) {
                    const int f0 = skk + 128 * j;
                    bf16x4 bv;
#pragma unroll
                    for (int q = 0; q < 4; ++q) bv[q] = (__bf16)xv[i * 4 + j][q];
                    *(bf16x4*)&Xs[r][f0 ^ rs] = bv;
                }
            }
        }
        LGKMCNT0; SBAR;                   // Xs visible to all waves

        // ---- (3) K loop: barrier-free, 2-slot ring, issue-after-compute ----
        floatx4 acc[4] = {{0,0,0,0},{0,0,0,0},{0,0,0,0},{0,0,0,0}};
        const char* wlrow0 = (const char*)&Wl[0][wave * 16 + l16][0];
        const char* wlrow1 = (const char*)&Wl[1][wave * 16 + l16][0];

        auto compute = [&](int slot, int s) {
            const char* wl = slot ? wlrow1 : wlrow0;
#pragma unroll
            for (int s2 = 0; s2 < 2; ++s2) {
                const int u0 = s2 * 8 + kgrp * 2;
                const floatx4 blo = *(const floatx4*)(wl + (((u0)     ^ l16) << 4));
                const floatx4 bhi = *(const floatx4*)(wl + (((u0 + 1) ^ l16) << 4));
                const bf16x8 bfrag = cvt8(blo, bhi);
                const int kb = (s * BK + s2 * 32 + kgrp * 8) ^ (h << 3);
#pragma unroll
                for (int mc = 0; mc < 4; ++mc) {
                    if (mc < nchunk) {
                        const bf16x8 afrag = *(const bf16x8*)&Xs[mc * 16 + l16][kb];
                        acc[mc] = __builtin_amdgcn_mfma_f32_16x16x32_bf16(
                                      afrag, bfrag, acc[mc], 0, 0, 0);
                    }
                }
            }
        };

#pragma unroll
        for (int i = 0; i < NSTEPS; ++i) {
            if (i < NSTEPS - 1) { VMCNT(4); } else { VMCNT(0); }
            SCHED0;
            compute(i & 1, i);            // lgkmcnt waits precede next issue
            if (i + 2 < NSTEPS) issue_step(i & 1, i + 2);
        }

        // ---- (4) epilogue: C/D layout col = lane&15, row = kgrp*4 + r ----
#pragma unroll
        for (int mc = 0; mc < 4; ++mc) {
            if (mc < nchunk) {
#pragma unroll
                for (int r = 0; r < 4; ++r) {
                    const int mloc = mc * 16 + kgrp * 4 + r;
                    if (mloc < rem)
                        out[(size_t)s_perm[m0 + mloc] * DD + ncol] =
                            acc[mc][r] + bias_v;
                }
            }
        }
        LGKMCNT0; SBAR;                   // Xs/ring safe to reuse next tile
    }
}

extern "C" void kernel_launch(void* const* d_in, const int* in_sizes, int n_in,
                              void* d_out, int out_size, void* d_ws, size_t ws_size,
                              hipStream_t stream) {
    const float* x      = (const float*)d_in[0];
    const int*   act    = (const int*)  d_in[1];
    const float* weight = (const float*)d_in[2];
    const float* bias   = (const float*)d_in[3];
    float*       out    = (float*)d_out;

    dl_fused<<<dim3(NA, DD / BN), 512, 0, stream>>>(x, act, weight, bias, out);
}

// Round 12
// 18.941 us; speedup vs baseline: 1.0255x; 1.0255x over previous
//
#include <hip/hip_runtime.h>

// DiscreteLinear: z[b,i] = sum_j weight[a[b],i,j] * x[b,j] + bias[a[b],i]
// B=2048, A=64, D=512.
// R11: 2 blocks/CU phase overlap. R7-R10 (five schedule variants) all tie
// at ~19.3us -> K-loop schedule is not the limiter; with 1 block/CU every
// serial phase (bucket scan, x stage, ramp, epilogue) leaves HBM idle.
// Now: BN=64 / 4 waves / M-tile 48 / LDS 69.6KB -> exactly 2 resident
// blocks per CU, so one block's serial phases overlap the other's DMA
// W-streaming K-loop. Ring mechanics identical to the proven R9/R10 core
// (per-wave rows, barrier-free counted vmcnt, 2-slot ring). perm stored
// as ushort to fit the 80KB/block budget.

#define NA 64
#define DD 512
#define NB 2048
#define BN 64           // output cols per block
#define NW 4            // waves per block
#define MT 48           // m-tile rows
#define BK 32           // fp32 k per ring step
#define NSTEPS 16       // DD / BK

typedef __bf16  bf16x8  __attribute__((ext_vector_type(8)));
typedef __bf16  bf16x4  __attribute__((ext_vector_type(4)));
typedef float   floatx4 __attribute__((ext_vector_type(4)));

#define GLD16(g, l)                                                         \
  __builtin_amdgcn_global_load_lds(                                         \
      (const __attribute__((address_space(1))) void*)(g),                   \
      (__attribute__((address_space(3))) void*)(l), 16, 0, 0)
#define VMCNT(n) asm volatile("s_waitcnt vmcnt(" #n ")" ::: "memory")
#define LGKMCNT0 asm volatile("s_waitcnt lgkmcnt(0)" ::: "memory")
#define SBAR     __builtin_amdgcn_s_barrier()
#define SCHED0   __builtin_amdgcn_sched_barrier(0)

static __device__ inline bf16x8 cvt8(floatx4 lo, floatx4 hi) {
    bf16x8 r;
    r[0] = (__bf16)lo[0]; r[1] = (__bf16)lo[1];
    r[2] = (__bf16)lo[2]; r[3] = (__bf16)lo[3];
    r[4] = (__bf16)hi[0]; r[5] = (__bf16)hi[1];
    r[6] = (__bf16)hi[2]; r[7] = (__bf16)hi[3];
    return r;
}

__global__ __launch_bounds__(256, 2) void dl_fused(
        const float* __restrict__ x,
        const int*   __restrict__ act,
        const float* __restrict__ weight,
        const float* __restrict__ bias,
        float*       __restrict__ out)
{
    const int a    = blockIdx.x;         // linear id = a + 64*y -> XCD = a%8:
    const int tid  = threadIdx.x;        // the 8 col-tiles of an action share
    const int wave = tid >> 6;           // an XCD -> x/act L2 reuse
    const int lane = tid & 63;
    const int l16  = lane & 15;
    const int kgrp = lane >> 4;
    const int h    = l16 & 7;
    const int colbase = blockIdx.y * BN;
    const int ncol    = colbase + wave * 16 + l16;

    __shared__ __align__(16) __bf16 Xs[MT][DD];        // 48 KB
    __shared__ __align__(16) float  Wl[2][BN][BK];     // 16 KB ring
    __shared__ unsigned short s_perm[NB];              // 4 KB
    __shared__ int s_wcnt[NW];

    const float* wtile = weight + (size_t)a * DD * DD + (size_t)colbase * DD;

    // DMA geometry: wave owns ring rows [wave*16,+16) = its own out cols.
    // Call c covers rows wave*16+c*8+r8; 16B unit u8 source-XORed by row&7
    // (rule #21: linear LDS dest + inverse-swizzled global source).
    const int r8 = lane >> 3;             // 0..7 row within call
    const int u8 = lane & 7;              // 0..7 16B unit within 128B slice

    auto issue_step = [&](int slot, int s) {
#pragma unroll
        for (int c = 0; c < 2; ++c)
            GLD16(wtile + (size_t)(wave * 16 + c * 8 + r8) * DD + s * BK
                        + ((u8 ^ r8) << 2),
                  (char*)&Wl[slot][wave * 16 + c * 8][0]);
    };

    // ---- act loads first (oldest), then early W DMA covering the bucket ----
    const int ibase = wave * (NB / NW);               // 512 samples per wave
    int myact[NB / NW / 64];                          // 8, regs
#pragma unroll
    for (int it = 0; it < NB / NW / 64; ++it)
        myact[it] = act[ibase + it * 64 + lane];

    issue_step(0, 0);
    issue_step(1, 1);                                 // 4 DMAs in flight

    // ---- fused bucket (raw barriers: no vmcnt(0) drain) ----
    int wcnt = 0;
#pragma unroll
    for (int it = 0; it < NB / NW / 64; ++it)
        wcnt += (int)__popcll(__ballot(myact[it] == a));
    if (lane == 0) s_wcnt[wave] = wcnt;
    LGKMCNT0; SBAR;
    int cnt = 0, off = 0;
#pragma unroll
    for (int v = 0; v < NW; ++v) {
        const int c = s_wcnt[v];
        if (v < wave) off += c;
        cnt += c;
    }
    if (cnt == 0) { VMCNT(0); return; }   // drain DMAs before LDS dealloc
#pragma unroll
    for (int it = 0; it < NB / NW / 64; ++it) {
        unsigned long long m = __ballot(myact[it] == a);
        if (myact[it] == a) {
            int pos = off + (int)__popcll(m & ((1ull << lane) - 1ull));
            s_perm[pos] = (unsigned short)(ibase + it * 64 + lane);
        }
        off += (int)__popcll(m);
    }
    LGKMCNT0; SBAR;                       // publish s_perm

    const float bias_v = bias[(size_t)a * DD + ncol];
    const int   srow   = tid >> 5;        // x staging: rows 0..7 (+8/pass)
    const int   skk    = (tid & 31) << 2; // 32 lanes x float4 per row

    for (int m0 = 0; m0 < cnt; m0 += MT) {
        if (m0 > 0) { issue_step(0, 0); issue_step(1, 1); }  // rare 2nd tile
        const int rem    = min(cnt - m0, MT);
        const int nchunk = (rem + 15) >> 4;               // <= 3

        // ---- x loads (clamped, unconditional defs; 24 float4 in flight) ----
        floatx4 xv[24];
#pragma unroll
        for (int i = 0; i < 6; ++i) {
            const int r  = srow + 8 * i;
            const int rr = (r < rem) ? r : (rem - 1);
            const float* xr = x + (size_t)s_perm[m0 + rr] * DD;
#pragma unroll
            for (int j = 0; j < 4; ++j)
                xv[i * 4 + j] = *(const floatx4*)(xr + skk + 128 * j);
        }
        // ---- cvt + swizzled Xs write (only live rows) ----
#pragma unroll
        for (int i = 0; i < 6; ++i) {
            const int r = srow + 8 * i;
            if (r < rem) {
                const int rs = (r & 7) << 3;
#pragma unroll
                for (int j = 0; j < 4; ++j) {
                    const int f0 = skk + 128 * j;
                    bf16x4 bv;
#pragma unroll
                    for (int q = 0; q < 4; ++q) bv[q] = (__bf16)xv[i * 4 + j][q];
                    *(bf16x4*)&Xs[r][f0 ^ rs] = bv;
                }
            }
        }
        LGKMCNT0; SBAR;                   // Xs visible to all waves

        // ---- K loop: barrier-free, 2-slot ring, per-wave counted vmcnt ----
        floatx4 acc[3] = {{0,0,0,0},{0,0,0,0},{0,0,0,0}};

        auto compute = [&](int slot, int s) {
            const char* wl = (const char*)&Wl[slot][wave * 16 + l16][0];
            const floatx4 blo = *(const floatx4*)(wl + (((2 * kgrp)     ^ h) << 4));
            const floatx4 bhi = *(const floatx4*)(wl + (((2 * kgrp + 1) ^ h) << 4));
            const bf16x8 bfrag = cvt8(blo, bhi);
            const int kb = (s * BK + kgrp * 8) ^ (h << 3);
#pragma unroll
            for (int mc = 0; mc < 3; ++mc) {
                if (mc < nchunk) {
                    const bf16x8 afrag = *(const bf16x8*)&Xs[mc * 16 + l16][kb];
                    acc[mc] = __builtin_amdgcn_mfma_f32_16x16x32_bf16(
                                  afrag, bfrag, acc[mc], 0, 0, 0);
                }
            }
        };

#pragma unroll
        for (int i = 0; i < NSTEPS; ++i) {
            if (i < NSTEPS - 1) { VMCNT(2); } else { VMCNT(0); }
            SCHED0;
            compute(i & 1, i);            // ds-read waits precede next issue
            if (i + 2 < NSTEPS) issue_step(i & 1, i + 2);
        }

        // ---- epilogue: C/D layout col = lane&15, row = kgrp*4 + r ----
#pragma unroll
        for (int mc = 0; mc < 3; ++mc) {
            if (mc < nchunk) {
#pragma unroll
                for (int r = 0; r < 4; ++r) {
                    const int mloc = mc * 16 + kgrp * 4 + r;
                    if (mloc < rem)
                        out[(size_t)s_perm[m0 + mloc] * DD + ncol] =
                            acc[mc][r] + bias_v;
                }
            }
        }
        LGKMCNT0; SBAR;                   // Xs/ring safe to reuse next tile
    }
}

extern "C" void kernel_launch(void* const* d_in, const int* in_sizes, int n_in,
                              void* d_out, int out_size, void* d_ws, size_t ws_size,
                              hipStream_t stream) {
    const float* x      = (const float*)d_in[0];
    const int*   act    = (const int*)  d_in[1];
    const float* weight = (const float*)d_in[2];
    const float* bias   = (const float*)d_in[3];
    float*       out    = (float*)d_out;

    dl_fused<<<dim3(NA, DD / BN), 256, 0, stream>>>(x, act, weight, bias, out);
}

// Round 13
// 18.860 us; speedup vs baseline: 1.0299x; 1.0043x over previous
//
#include <hip/hip_runtime.h>

// DiscreteLinear: z[b,i] = sum_j weight[a[b],i,j] * x[b,j] + bias[a[b],i]
// B=2048, A=64, D=512.
// R12 = R11 (2 blocks/CU, BN=64, MT=48, fused bucket, per-wave DMA ring)
// with a 3-slot ring: entry burst covers 3 steps (6 calls/wave in flight
// through the bucket+stage phases) and the steady-state wait is vmcnt(4)
// (2 iterations of slack vs R11's 1) -> covers ~400-500cy L3 latency.
// Tests theory T-B (exposed ring latency) vs T-A (ingress ceiling ~7TB/s).

#define NA 64
#define DD 512
#define NB 2048
#define BN 64           // output cols per block
#define NW 4            // waves per block
#define MT 48           // m-tile rows
#define BK 32           // fp32 k per ring step
#define NSTEPS 16       // DD / BK
#define NSLOT 3         // ring slots

typedef __bf16  bf16x8  __attribute__((ext_vector_type(8)));
typedef __bf16  bf16x4  __attribute__((ext_vector_type(4)));
typedef float   floatx4 __attribute__((ext_vector_type(4)));

#define GLD16(g, l)                                                         \
  __builtin_amdgcn_global_load_lds(                                         \
      (const __attribute__((address_space(1))) void*)(g),                   \
      (__attribute__((address_space(3))) void*)(l), 16, 0, 0)
#define VMCNT(n) asm volatile("s_waitcnt vmcnt(" #n ")" ::: "memory")
#define LGKMCNT0 asm volatile("s_waitcnt lgkmcnt(0)" ::: "memory")
#define SBAR     __builtin_amdgcn_s_barrier()
#define SCHED0   __builtin_amdgcn_sched_barrier(0)

static __device__ inline bf16x8 cvt8(floatx4 lo, floatx4 hi) {
    bf16x8 r;
    r[0] = (__bf16)lo[0]; r[1] = (__bf16)lo[1];
    r[2] = (__bf16)lo[2]; r[3] = (__bf16)lo[3];
    r[4] = (__bf16)hi[0]; r[5] = (__bf16)hi[1];
    r[6] = (__bf16)hi[2]; r[7] = (__bf16)hi[3];
    return r;
}

__global__ __launch_bounds__(256, 2) void dl_fused(
        const float* __restrict__ x,
        const int*   __restrict__ act,
        const float* __restrict__ weight,
        const float* __restrict__ bias,
        float*       __restrict__ out)
{
    const int a    = blockIdx.x;         // linear id = a + 64*y -> XCD = a%8:
    const int tid  = threadIdx.x;        // the 8 col-tiles of an action share
    const int wave = tid >> 6;           // an XCD -> x/act L2 reuse
    const int lane = tid & 63;
    const int l16  = lane & 15;
    const int kgrp = lane >> 4;
    const int h    = l16 & 7;
    const int colbase = blockIdx.y * BN;
    const int ncol    = colbase + wave * 16 + l16;

    __shared__ __align__(16) __bf16 Xs[MT][DD];        // 48 KB
    __shared__ __align__(16) float  Wl[NSLOT][BN][BK]; // 24 KB ring
    __shared__ unsigned short s_perm[NB];              // 4 KB
    __shared__ int s_wcnt[NW];

    const float* wtile = weight + (size_t)a * DD * DD + (size_t)colbase * DD;

    // DMA geometry: wave owns ring rows [wave*16,+16) = its own out cols.
    // Call c covers rows wave*16+c*8+r8; 16B unit u8 source-XORed by row&7
    // (rule #21: linear LDS dest + inverse-swizzled global source).
    const int r8 = lane >> 3;             // 0..7 row within call
    const int u8 = lane & 7;              // 0..7 16B unit within 128B slice

    auto issue_step = [&](int slot, int s) {
#pragma unroll
        for (int c = 0; c < 2; ++c)
            GLD16(wtile + (size_t)(wave * 16 + c * 8 + r8) * DD + s * BK
                        + ((u8 ^ r8) << 2),
                  (char*)&Wl[slot][wave * 16 + c * 8][0]);
    };

    // ---- act loads first (oldest vm ops), then entry DMA burst ----
    const int ibase = wave * (NB / NW);               // 512 samples per wave
    int myact[NB / NW / 64];                          // 8, regs
#pragma unroll
    for (int it = 0; it < NB / NW / 64; ++it)
        myact[it] = act[ibase + it * 64 + lane];

    issue_step(0, 0);
    issue_step(1, 1);
    issue_step(2, 2);                                 // 6 DMAs in flight

    // ---- fused bucket (raw barriers: no vmcnt(0) drain) ----
    int wcnt = 0;
#pragma unroll
    for (int it = 0; it < NB / NW / 64; ++it)
        wcnt += (int)__popcll(__ballot(myact[it] == a));
    if (lane == 0) s_wcnt[wave] = wcnt;
    LGKMCNT0; SBAR;
    int cnt = 0, off = 0;
#pragma unroll
    for (int v = 0; v < NW; ++v) {
        const int c = s_wcnt[v];
        if (v < wave) off += c;
        cnt += c;
    }
    if (cnt == 0) { VMCNT(0); return; }   // drain DMAs before LDS dealloc
#pragma unroll
    for (int it = 0; it < NB / NW / 64; ++it) {
        unsigned long long m = __ballot(myact[it] == a);
        if (myact[it] == a) {
            int pos = off + (int)__popcll(m & ((1ull << lane) - 1ull));
            s_perm[pos] = (unsigned short)(ibase + it * 64 + lane);
        }
        off += (int)__popcll(m);
    }
    LGKMCNT0; SBAR;                       // publish s_perm

    const float bias_v = bias[(size_t)a * DD + ncol];
    const int   srow   = tid >> 5;        // x staging: rows 0..7 (+8/pass)
    const int   skk    = (tid & 31) << 2; // 32 lanes x float4 per row

    for (int m0 = 0; m0 < cnt; m0 += MT) {
        if (m0 > 0) {                     // rare 2nd tile: restart ring
            issue_step(0, 0); issue_step(1, 1); issue_step(2, 2);
        }
        const int rem    = min(cnt - m0, MT);
        const int nchunk = (rem + 15) >> 4;               // <= 3

        // ---- x loads (clamped, unconditional defs; 24 float4 in flight) ----
        floatx4 xv[24];
#pragma unroll
        for (int i = 0; i < 6; ++i) {
            const int r  = srow + 8 * i;
            const int rr = (r < rem) ? r : (rem - 1);
            const float* xr = x + (size_t)s_perm[m0 + rr] * DD;
#pragma unroll
            for (int j = 0; j < 4; ++j)
                xv[i * 4 + j] = *(const floatx4*)(xr + skk + 128 * j);
        }
        // ---- cvt + swizzled Xs write (only live rows) ----
#pragma unroll
        for (int i = 0; i < 6; ++i) {
            const int r = srow + 8 * i;
            if (r < rem) {
                const int rs = (r & 7) << 3;
#pragma unroll
                for (int j = 0; j < 4; ++j) {
                    const int f0 = skk + 128 * j;
                    bf16x4 bv;
#pragma unroll
                    for (int q = 0; q < 4; ++q) bv[q] = (__bf16)xv[i * 4 + j][q];
                    *(bf16x4*)&Xs[r][f0 ^ rs] = bv;
                }
            }
        }
        LGKMCNT0; SBAR;                   // Xs visible to all waves

        // ---- K loop: barrier-free, 3-slot ring, per-wave counted vmcnt ----
        floatx4 acc[3] = {{0,0,0,0},{0,0,0,0},{0,0,0,0}};

        auto compute = [&](int slot, int s) {
            const char* wl = (const char*)&Wl[slot][wave * 16 + l16][0];
            const floatx4 blo = *(const floatx4*)(wl + (((2 * kgrp)     ^ h) << 4));
            const floatx4 bhi = *(const floatx4*)(wl + (((2 * kgrp + 1) ^ h) << 4));
            const bf16x8 bfrag = cvt8(blo, bhi);
            const int kb = (s * BK + kgrp * 8) ^ (h << 3);
#pragma unroll
            for (int mc = 0; mc < 3; ++mc) {
                if (mc < nchunk) {
                    const bf16x8 afrag = *(const bf16x8*)&Xs[mc * 16 + l16][kb];
                    acc[mc] = __builtin_amdgcn_mfma_f32_16x16x32_bf16(
                                  afrag, bfrag, acc[mc], 0, 0, 0);
                }
            }
        };

        // steady: wait step i (vmcnt 4 = 2 iters slack), compute, issue i+3
        // into slot i%3 (just consumed; DMA lands >=1 latency later, ds_reads
        // long retired -- proven-safe issue-after-compute reuse).
#pragma unroll
        for (int i = 0; i < NSTEPS; ++i) {
            if (i < NSTEPS - 2)       { VMCNT(4); }
            else if (i == NSTEPS - 2) { VMCNT(2); }
            else                      { VMCNT(0); }
            SCHED0;
            compute(i % NSLOT, i);
            if (i + NSLOT < NSTEPS) issue_step(i % NSLOT, i + NSLOT);
        }

        // ---- epilogue: C/D layout col = lane&15, row = kgrp*4 + r ----
#pragma unroll
        for (int mc = 0; mc < 3; ++mc) {
            if (mc < nchunk) {
#pragma unroll
                for (int r = 0; r < 4; ++r) {
                    const int mloc = mc * 16 + kgrp * 4 + r;
                    if (mloc < rem)
                        out[(size_t)s_perm[m0 + mloc] * DD + ncol] =
                            acc[mc][r] + bias_v;
                }
            }
        }
        LGKMCNT0; SBAR;                   // Xs/ring safe to reuse next tile
    }
}

extern "C" void kernel_launch(void* const* d_in, const int* in_sizes, int n_in,
                              void* d_out, int out_size, void* d_ws, size_t ws_size,
                              hipStream_t stream) {
    const float* x      = (const float*)d_in[0];
    const int*   act    = (const int*)  d_in[1];
    const float* weight = (const float*)d_in[2];
    const float* bias   = (const float*)d_in[3];
    float*       out    = (float*)d_out;

    dl_fused<<<dim3(NA, DD / BN), 256, 0, stream>>>(x, act, weight, bias, out);
}